// Round 2
// baseline (632.908 us; speedup 1.0000x reference)
//
#include <hip/hip_runtime.h>
#include <hip/hip_bf16.h>

#define NN 50000
#define NE 800000
#define C  64

// ---- dtype-flexible load/store helpers (mode: 0 = fp32, 1 = bf16) -------
__device__ __forceinline__ float ldv(const void* p, int i, int mode) {
    return mode ? __bfloat162float(((const __hip_bfloat16*)p)[i])
                : ((const float*)p)[i];
}
__device__ __forceinline__ void stv(void* p, int i, int mode, float v) {
    if (mode) ((__hip_bfloat16*)p)[i] = __float2bfloat16(v);
    else      ((float*)p)[i] = v;
}
// logical index i of edge array; i64: element stride 2 words, low word = value
__device__ __forceinline__ int ldix(const int* ei, int i, int i64) {
    return i64 ? ei[2 * i] : ei[i];
}

// ---- probe: detect float dtype of x and int width of edge_index ---------
// bf16-packed x ~ N(0,1): low 16 bits of each 32b word are a bf16 value whose
// high byte (sans sign) lands in [0x37,0x41] nearly always. fp32 x: low 16
// bits are mantissa bits (~uniform) -> ~9% hit rate. Threshold 64/128.
// int64 edge_index: odd 32b words are high halves == 0 (values < 2^31).
__global__ void probe_kernel(const unsigned* __restrict__ xw,
                             const int* __restrict__ eiw,
                             int* __restrict__ flags) {
    if (threadIdx.x != 0 || blockIdx.x != 0) return;
    int hits = 0;
    for (int i = 0; i < 128; ++i) {
        unsigned hb = (xw[i] >> 8) & 0x7Fu;
        if (hb >= 0x37u && hb <= 0x41u) hits++;
    }
    flags[0] = (hits >= 64) ? 1 : 0;   // 1 = floats are bf16
    int zeros = 0;
    for (int i = 1; i < 256; i += 2) if (eiw[i] == 0) zeros++;
    flags[1] = (zeros >= 64) ? 1 : 0;  // 1 = edge_index is int64
}

// ---- degree: count src occurrences --------------------------------------
__global__ void deg_kernel(const int* __restrict__ ei, const int* __restrict__ flags,
                           unsigned* __restrict__ deg) {
    int e = blockIdx.x * blockDim.x + threadIdx.x;
    if (e < NE) atomicAdd(&deg[ldix(ei, e, flags[1])], 1u);
}

// ---- dis = deg > 0 ? deg^-0.5 : 0 ---------------------------------------
__global__ void dis_kernel(const unsigned* __restrict__ deg, float* __restrict__ dis) {
    int i = blockIdx.x * blockDim.x + threadIdx.x;
    if (i < NN) {
        unsigned d = deg[i];
        dis[i] = (d > 0u) ? rsqrtf((float)d) : 0.0f;
    }
}

// ---- scatter: y[dst] += -(dis[src]*dis[dst]) * x[src]  (wave per edge) --
__global__ void scatter_kernel(const void* __restrict__ x, const int* __restrict__ ei,
                               const int* __restrict__ flags, const float* __restrict__ dis,
                               float* __restrict__ y, int xmode) {
    int gw = (blockIdx.x * blockDim.x + threadIdx.x) >> 6;
    int lane = threadIdx.x & 63;
    if (gw >= NE) return;
    int i64 = flags[1];
    int xm = (xmode == 2) ? flags[0] : xmode;
    int s = ldix(ei, gw, i64);
    int d = ldix(ei, NE + gw, i64);
    float w = -dis[s] * dis[d];
    atomicAdd(&y[d * C + lane], ldv(x, s * C + lane, xm) * w);
}

// ---- per-node dual GEMM: out = act(x@W0 + y@W1 + b) ---------------------
// wave per row, lane per output column; weights staged fp32 in LDS.
__global__ void cheb_gemm(const void* __restrict__ x, const float* __restrict__ y,
                          const void* __restrict__ W0, const void* __restrict__ W1,
                          const void* __restrict__ b, void* out,
                          const int* __restrict__ flags,
                          int xmode, int outmode, int do_relu) {
    __shared__ float W0s[C][C];
    __shared__ float W1s[C][C];
    __shared__ float bs[C];
    int wm = flags[0];                       // weights share the input float dtype
    int xm = (xmode == 2) ? flags[0] : xmode;
    int om = (outmode == 2) ? flags[0] : outmode;
    int tid = threadIdx.x;
    for (int i = tid; i < C * C; i += blockDim.x) {
        W0s[i >> 6][i & 63] = ldv(W0, i, wm);
        W1s[i >> 6][i & 63] = ldv(W1, i, wm);
    }
    if (tid < C) bs[tid] = ldv(b, tid, wm);
    __syncthreads();

    int wave = tid >> 6;
    int lane = tid & 63;
    for (int r = blockIdx.x * 4 + wave; r < NN; r += gridDim.x * 4) {
        const float* yr = y + r * C;
        float acc = bs[lane];
#pragma unroll 8
        for (int k = 0; k < C; ++k) {
            acc += ldv(x, r * C + k, xm) * W0s[k][lane];
            acc += yr[k] * W1s[k][lane];
        }
        if (do_relu) acc = fmaxf(acc, 0.0f);
        stv(out, r * C + lane, om, acc);
    }
}

extern "C" void kernel_launch(void* const* d_in, const int* in_sizes, int n_in,
                              void* d_out, int out_size, void* d_ws, size_t ws_size,
                              hipStream_t stream) {
    const void* x    = d_in[0];
    const int*  ei   = (const int*)d_in[1];
    const void* W1_0 = d_in[2];
    const void* W1_1 = d_in[3];
    const void* b1   = d_in[4];
    const void* W2_0 = d_in[5];
    const void* W2_1 = d_in[6];
    const void* b2   = d_in[7];

    char* ws = (char*)d_ws;
    unsigned* deg   = (unsigned*)(ws);                 // 200 KB used
    float*    dis   = (float*)(ws + 256 * 1024);       // 200 KB used
    int*      flags = (int*)(ws + 496 * 1024);         // 16 B
    float*    y     = (float*)(ws + 512 * 1024);       // 12.8 MB
    char*     h     = ws + 512 * 1024 + 13 * 1024 * 1024;

    // h precision: fp32 if workspace allows (26.5 MB), else bf16 (19.9 MB)
    const size_t need_f32 = 512u * 1024 + 13u * 1024 * 1024 + 13u * 1024 * 1024;
    int hmode = (ws_size >= need_f32) ? 0 : 1;

    probe_kernel<<<1, 1, 0, stream>>>((const unsigned*)x, ei, flags);

    hipMemsetAsync(deg, 0, NN * sizeof(unsigned), stream);
    hipMemsetAsync(y, 0, (size_t)NN * C * sizeof(float), stream);

    deg_kernel<<<(NE + 255) / 256, 256, 0, stream>>>(ei, flags, deg);
    dis_kernel<<<(NN + 255) / 256, 256, 0, stream>>>(deg, dis);

    // layer 1: y = Lhat @ x ; h = relu(x@W1_0 + y@W1_1 + b1)
    scatter_kernel<<<(NE * 64) / 256, 256, 0, stream>>>(x, ei, flags, dis, y, 2);
    cheb_gemm<<<1024, 256, 0, stream>>>(x, y, W1_0, W1_1, b1, h, flags, 2, hmode, 1);

    // layer 2: y = Lhat @ h ; out = h@W2_0 + y@W2_1 + b2
    hipMemsetAsync(y, 0, (size_t)NN * C * sizeof(float), stream);
    scatter_kernel<<<(NE * 64) / 256, 256, 0, stream>>>(h, ei, flags, dis, y, hmode);
    cheb_gemm<<<1024, 256, 0, stream>>>(h, y, W2_0, W2_1, b2, d_out, flags, hmode, 2, 0);
}